// Round 12
// baseline (438.274 us; speedup 1.0000x reference)
//
#include <hip/hip_runtime.h>
#include <cstdint>

#define S_LEN 2048
#define B_SZ 8
#define D_DIM 2048
#define M_DIM (S_LEN * B_SZ)   // 16384 tokens
#define CHAINS (B_SZ * D_DIM)  // 16384 scan chains
#define BK 64
#define KTILES (D_DIM / BK)    // 32

typedef __bf16 bf16;
typedef bf16 bf16x8 __attribute__((ext_vector_type(8)));
typedef bf16 bf16x4 __attribute__((ext_vector_type(4)));
typedef float f32x4 __attribute__((ext_vector_type(4)));

__device__ __forceinline__ void async_copy16(void* lds, const void* g) {
    __builtin_amdgcn_global_load_lds(
        (const __attribute__((address_space(1))) unsigned int*)g,
        (__attribute__((address_space(3))) unsigned int*)lds,
        16, 0, 0);
}

__device__ __forceinline__ unsigned short bf16_bits(float f) {
    bf16 b = (bf16)f;
    return __builtin_bit_cast(unsigned short, b);
}

// ---------------- fp32 -> bf16; x flat, W in MFMA-fragment order -------------
// W frag id: frag = ((nb*32 + kt)*32) + cg*2 + ks   (nb: 256-col N-block in
// interleaved space, kt: K-tile, cg: 16-col group 0..15, ks: K-half)
// frag holds 64 lanes x 8 bf16: lane = (col&15) + chunk*16, elems k =
// kt*64 + ks*32 + chunk*8 .. +7 of interleaved row r = nb*256 + cg*16 + (col&15).
// Interleave: r = (e>>4)*32 + gate*16 + (e&15).
__global__ void k_convert(const float4* __restrict__ x,
                          const float4* __restrict__ wx,
                          const float4* __restrict__ wa,
                          bf16* __restrict__ xb,
                          bf16* __restrict__ wsw) {
    const long NX4 = (long)M_DIM * D_DIM / 4;   // 8388608 float4 items
    const long NWS = 1048576;                   // W dest slots (8 bf16 each)
    const long total = NX4 + NWS;
    for (long i = (long)blockIdx.x * blockDim.x + threadIdx.x; i < total;
         i += (long)gridDim.x * blockDim.x) {
        if (i < NX4) {
            float4 v = x[i];
            bf16x4 o;
            o[0] = (bf16)v.x; o[1] = (bf16)v.y; o[2] = (bf16)v.z; o[3] = (bf16)v.w;
            *reinterpret_cast<bf16x4*>(xb + 4 * i) = o;
        } else {
            const long t = i - NX4;             // dest slot
            const int lane = (int)(t & 63);
            const long frag = t >> 6;
            const int ks = (int)(frag & 1);
            const int cg = (int)((frag >> 1) & 15);
            const int kt = (int)((frag >> 5) & 31);
            const int nb = (int)(frag >> 10);
            const int lr = lane & 15, ch = lane >> 4;
            const int g  = cg & 1;                       // gate (nb*16 even)
            const int e  = (((nb << 4) | cg) >> 1) * 16 + lr;  // source row
            const int d  = kt * 64 + ks * 32 + ch * 8;         // source col
            const float4* src = (g ? wa : wx) + (long)e * 512 + (d >> 2);
            const float4 v0 = src[0];
            const float4 v1 = src[1];
            bf16x8 o;
            o[0] = (bf16)v0.x; o[1] = (bf16)v0.y;
            o[2] = (bf16)v0.z; o[3] = (bf16)v0.w;
            o[4] = (bf16)v1.x; o[5] = (bf16)v1.y;
            o[6] = (bf16)v1.z; o[7] = (bf16)v1.w;
            *reinterpret_cast<bf16x8*>(wsw + t * 8) = o;
        }
    }
}

__global__ void k_cvec(const float* __restrict__ ap, float* __restrict__ cv) {
    int e = blockIdx.x * blockDim.x + threadIdx.x;
    if (e < D_DIM) {
        float v = ap[e];
        cv[e] = -8.0f * log1pf(expf(v));
    }
}

// ---------------- GEMM: A via LDS dbuf, B register-direct from global --------
// C = xb[16384x2048] @ W^T, tile 256x256(interleaved)x64, 8 waves (2M x 4N).
// LDS: A only, 2 x 32KB (256 rows x 128B, XOR-swizzled).  B frags loaded
// straight to registers from fragment-ordered wsw, prefetched 1 tile ahead.
// One barrier per K-tile.  Boundary vmcnt(8): 4 A-stages (older) drained,
// 8 B-loads (newer) stay in flight.
__global__ __launch_bounds__(512, 2) void k_gemm(
    const bf16* __restrict__ xb,    // [M][D] bf16
    const bf16* __restrict__ wsw,   // fragment-ordered W
    const float* __restrict__ bx,
    const float* __restrict__ ba,
    const float* __restrict__ cv,
    unsigned int* __restrict__ pk)  // [M][D] packed (xn<<16 | la)
{
    __shared__ __align__(16) char smem[65536];  // 2 x 32KB A buffers

    const int tid  = threadIdx.x;
    const int lane = tid & 63;
    const int w    = tid >> 6;       // 8 waves
    const int wm   = w >> 2;         // 0..1 (128 rows each)
    const int wn   = w & 3;          // 0..3 (64 interleaved cols each)

    const int orig = blockIdx.x;
    const int wgid = (orig & 7) * 128 + (orig >> 3);
    const int m0  = (wgid & 63) * 256;   // 64 M-blocks
    const int nbb = wgid >> 6;           // 16 N-blocks (interleaved)
    const int e0  = nbb * 256;

    const int srow  = lane >> 3;                 // 0..7
    const int swz16 = ((lane & 7) ^ srow) * 16;  // inverse-swizzled src chunk
    const int rL = lane & 15;

    const char* gA = (const char*)xb;

#define SU_A(buf, kt, u) do {                                                  \
    const int rb_ = (u) * 64 + w * 8;                                          \
    async_copy16(smem + (buf) * 32768 + rb_ * 128,                             \
                 gA + ((long)(m0 + rb_ + srow) * 4096 +                        \
                       (long)(kt) * 128 + swz16));                             \
    } while (0)

// load this wave's 8 B-frags of K-tile kt into dst[j*2+ks] (registers)
#define LOAD_BG(dst, kt) do {                                                  \
    _Pragma("unroll")                                                          \
    for (int j_ = 0; j_ < 4; ++j_)                                             \
        _Pragma("unroll")                                                      \
        for (int ks_ = 0; ks_ < 2; ++ks_)                                      \
            dst[j_ * 2 + ks_] = *reinterpret_cast<const bf16x8*>(              \
                wsw + ((((long)nbb * 32 + (kt)) * 32) +                        \
                       (wn * 4 + j_) * 2 + ks_) * 512 + lane * 8);             \
    } while (0)

#define LOAD_AF(ihalf, ks) do {                                                \
    _Pragma("unroll")                                                          \
    for (int i_ = 0; i_ < 4; ++i_) {                                           \
        const int r_ = wm * 128 + ((ihalf) * 4 + i_) * 16 + rL;                \
        const int ch_ = (((ks) * 4 + (lane >> 4)) ^ (r_ & 7)) * 16;            \
        af[i_] = *reinterpret_cast<const bf16x8*>(sA + r_ * 128 + ch_);        \
    } } while (0)

#define MFMA16(ihalf, ks, bm) do {                                             \
    _Pragma("unroll")                                                          \
    for (int i_ = 0; i_ < 4; ++i_)                                             \
        _Pragma("unroll")                                                      \
        for (int j_ = 0; j_ < 4; ++j_)                                         \
            acc[(ihalf) * 4 + i_][j_] =                                        \
                __builtin_amdgcn_mfma_f32_16x16x32_bf16(                       \
                    af[i_], bm[j_ * 2 + (ks)],                                 \
                    acc[(ihalf) * 4 + i_][j_], 0, 0, 0);                       \
    } while (0)

    f32x4 acc[8][4];
#pragma unroll
    for (int i = 0; i < 8; ++i)
#pragma unroll
        for (int j = 0; j < 4; ++j) acc[i][j] = (f32x4)(0.0f);

    bf16x8 b0[8], b1[8];

    // prologue: stage A(0), then B(0) to regs; drain stages only (vmcnt(8))
    SU_A(0, 0, 0); SU_A(0, 0, 1); SU_A(0, 0, 2); SU_A(0, 0, 3);
    asm volatile("" ::: "memory");   // keep stage issues before B loads
    LOAD_BG(b0, 0);
    asm volatile("s_waitcnt vmcnt(8)" ::: "memory");
    __builtin_amdgcn_s_barrier();

#define TILE(kt, bcur, bnxt) do {                                              \
    const int c_ = (kt) & 1;                                                   \
    const char* sA = smem + c_ * 32768;                                        \
    const bool pf_ = (kt) < KTILES - 1;                                        \
    bf16x8 af[4];                                                              \
    if (pf_) {                                                                 \
        SU_A(1 - c_, (kt) + 1, 0); SU_A(1 - c_, (kt) + 1, 1);                  \
        SU_A(1 - c_, (kt) + 1, 2); SU_A(1 - c_, (kt) + 1, 3);                  \
        asm volatile("" ::: "memory");  /* stages before B loads */            \
        LOAD_BG(bnxt, (kt) + 1);                                               \
    }                                                                          \
    LOAD_AF(0, 0); MFMA16(0, 0, bcur);                                         \
    LOAD_AF(1, 0); MFMA16(1, 0, bcur);                                         \
    LOAD_AF(0, 1); MFMA16(0, 1, bcur);                                         \
    LOAD_AF(1, 1); MFMA16(1, 1, bcur);                                         \
    if (pf_) {                                                                 \
        asm volatile("s_waitcnt vmcnt(8)" ::: "memory");                       \
        __builtin_amdgcn_s_barrier();                                          \
    }                                                                          \
    } while (0)

    for (int it = 0; it < KTILES / 2; ++it) {
        TILE(2 * it, b0, b1);
        TILE(2 * it + 1, b1, b0);
    }

#undef TILE
#undef SU_A
#undef LOAD_BG
#undef LOAD_AF
#undef MFMA16

    // ---- epilogue: gates in-register, pack (bf16 xn | bf16 la) ----
    const int rgrp = lane >> 4;
    const int chb  = (e0 + wn * 64) >> 1;  // real channel base for this wave
#pragma unroll
    for (int jj = 0; jj < 2; ++jj) {
        const int ch = chb + jj * 16 + rL;
        const float bxv = bx[ch];
        const float bav = ba[ch];
        const float cvv = cv[ch];
#pragma unroll
        for (int i = 0; i < 8; ++i) {
#pragma unroll
            for (int r = 0; r < 4; ++r) {
                const int m = m0 + wm * 128 + i * 16 + rgrp * 4 + r;
                const float zx = acc[i][2 * jj][r] + bxv;
                const float za = acc[i][2 * jj + 1][r] + bav;
                const float gx = 1.0f / (1.0f + __expf(-zx));
                const float ga = 1.0f / (1.0f + __expf(-za));
                float la = cvv * ga;
                float mult = sqrtf(fmaxf(1.0f - __expf(2.0f * la), 0.0f));
                if (m < B_SZ) { la = -100.0f; mult = 1.0f; }  // s==0 reset
                const long o = (long)m * D_DIM + ch;
                const float xv = (float)xb[o];
                const float xn = xv * gx * mult;
                const unsigned int u =
                    ((unsigned int)bf16_bits(xn) << 16) | bf16_bits(la);
                pk[o] = u;
            }
        }
    }
}

// ---------------- scan: h = exp(la)*h + xn over S, y <- h --------------------
__global__ __launch_bounds__(64) void k_scan(
    const unsigned int* __restrict__ pk,
    float* __restrict__ y,
    const float* __restrict__ h0,
    float* __restrict__ hn) {
    const int c = blockIdx.x * 64 + threadIdx.x;  // chain id
    float h = h0[c];

    unsigned int u0[16], u1[16];
#pragma unroll
    for (int j = 0; j < 16; ++j) u0[j] = pk[(long)j * CHAINS + c];

    for (int g = 0; g < 128; g += 2) {
        const long base1 = ((long)(g + 1) * 16) * CHAINS + c;
        if (g + 1 < 128) {
#pragma unroll
            for (int j = 0; j < 16; ++j) u1[j] = pk[base1 + (long)j * CHAINS];
        }
        const long base0 = ((long)g * 16) * CHAINS + c;
#pragma unroll
        for (int j = 0; j < 16; ++j) {
            const unsigned int u = u0[j];
            const float la = __builtin_bit_cast(float, u << 16);
            const float xn = __builtin_bit_cast(float, u & 0xffff0000u);
            h = fmaf(__expf(la), h, xn);
            y[base0 + (long)j * CHAINS] = h;
        }
        const long base2 = ((long)(g + 2) * 16) * CHAINS + c;
        if (g + 2 < 128) {
#pragma unroll
            for (int j = 0; j < 16; ++j) u0[j] = pk[base2 + (long)j * CHAINS];
        }
        if (g + 1 < 128) {
#pragma unroll
            for (int j = 0; j < 16; ++j) {
                const unsigned int u = u1[j];
                const float la = __builtin_bit_cast(float, u << 16);
                const float xn = __builtin_bit_cast(float, u & 0xffff0000u);
                h = fmaf(__expf(la), h, xn);
                y[base1 + (long)j * CHAINS] = h;
            }
        }
    }
    hn[c] = h;
}

// ---------------- launch -----------------------------------------------------
extern "C" void kernel_launch(void* const* d_in, const int* in_sizes, int n_in,
                              void* d_out, int out_size, void* d_ws, size_t ws_size,
                              hipStream_t stream) {
    const float* x  = (const float*)d_in[0];
    const float* h0 = (const float*)d_in[1];
    const float* Wx = (const float*)d_in[2];
    const float* bx = (const float*)d_in[3];
    const float* Wa = (const float*)d_in[4];
    const float* ba = (const float*)d_in[5];
    const float* ap = (const float*)d_in[6];
    float* out = (float*)d_out;

    char* ws = (char*)d_ws;
    // ws: xb 0..64MiB | wsw 64..80MiB | cv @80MiB | pk @80MiB+8KiB (64MiB)
    bf16*  xb  = (bf16*)(ws);
    bf16*  wsw = (bf16*)(ws + 67108864L);
    float* cv  = (float*)(ws + 83886080L);
    unsigned int* pk = (unsigned int*)(ws + 83894272L);

    float* y  = out;                         // S*B*D
    float* hn = out + (long)M_DIM * D_DIM;   // B*D

    k_convert<<<dim3(2048), dim3(256), 0, stream>>>(
        (const float4*)x, (const float4*)Wx, (const float4*)Wa, xb, wsw);
    k_cvec<<<dim3(8), dim3(256), 0, stream>>>(ap, cv);
    k_gemm<<<dim3((M_DIM / 256) * (2 * D_DIM / 256)), dim3(512), 0, stream>>>(
        xb, wsw, bx, ba, cv, pk);
    k_scan<<<dim3(CHAINS / 64), dim3(64), 0, stream>>>(pk, y, h0, hn);
}

// Round 13
// 414.232 us; speedup vs baseline: 1.0580x; 1.0580x over previous
//
#include <hip/hip_runtime.h>
#include <cstdint>

#define S_LEN 2048
#define B_SZ 8
#define D_DIM 2048
#define M_DIM (S_LEN * B_SZ)   // 16384 tokens
#define CHAINS (B_SZ * D_DIM)  // 16384 scan chains
#define BK 64
#define KTILES (D_DIM / BK)    // 32

typedef __bf16 bf16;
typedef bf16 bf16x8 __attribute__((ext_vector_type(8)));
typedef bf16 bf16x4 __attribute__((ext_vector_type(4)));
typedef float f32x4 __attribute__((ext_vector_type(4)));

__device__ __forceinline__ void async_copy16(void* lds, const void* g) {
    __builtin_amdgcn_global_load_lds(
        (const __attribute__((address_space(1))) unsigned int*)g,
        (__attribute__((address_space(3))) unsigned int*)lds,
        16, 0, 0);
}

__device__ __forceinline__ unsigned short bf16_bits(float f) {
    bf16 b = (bf16)f;
    return __builtin_bit_cast(unsigned short, b);
}

// ---------------- fp32 -> bf16 conversion; W interleaved 16-row blocks -------
__global__ void k_convert(const float4* __restrict__ x,
                          const float4* __restrict__ wx,
                          const float4* __restrict__ wa,
                          bf16* __restrict__ xb,
                          bf16* __restrict__ wi) {
    const long NX4 = (long)M_DIM * D_DIM / 4;   // 8388608
    const long NW4 = (long)D_DIM * D_DIM / 4;   // 1048576
    const long total = NX4 + 2 * NW4;
    for (long i = (long)blockIdx.x * blockDim.x + threadIdx.x; i < total;
         i += (long)gridDim.x * blockDim.x) {
        float4 v;
        bf16* dst;
        if (i < NX4) {
            v = x[i];
            dst = xb + 4 * i;
        } else {
            long k = i - NX4;
            const int isA = k >= NW4;
            if (isA) k -= NW4;
            const long e = k >> 9;          // source channel row
            const long col4 = k & 511;
            const long drow = (e >> 4) * 32 + (isA ? 16 : 0) + (e & 15);
            v = (isA ? wa : wx)[k];
            dst = wi + (drow * 512 + col4) * 4;
        }
        bf16x4 o;
        o[0] = (bf16)v.x; o[1] = (bf16)v.y; o[2] = (bf16)v.z; o[3] = (bf16)v.w;
        *reinterpret_cast<bf16x4*>(dst) = o;
    }
}

__global__ void k_cvec(const float* __restrict__ ap, float* __restrict__ cv) {
    int e = blockIdx.x * blockDim.x + threadIdx.x;
    if (e < D_DIM) {
        float v = ap[e];
        cv[e] = -8.0f * log1pf(expf(v));
    }
}

// ---------------- single GEMM, counted-vmcnt unit-staggered staging ----------
// (verbatim restore of the best-measured variant: 334 us, MfmaUtil 36.3)
// C = xb[16384x2048] @ wi[4096x2048]^T, tile 256x256xBK64, 8 waves (2M x 4N).
// LDS buffer: A [256][128B] @0 | B [256][128B] @32KB; 2 buffers (128KB).
// Staging unit = 64 rows (8KB), 1 instr/wave/unit.  Per tile t, stage t+1:
//   ph0:{A0,A2} ph1:{B0,B1} ph2:{B2,B3} ph3:{A1,A3}
// Waits: after-ph0 vmcnt(2)+bar (A1,A3 of t); boundary vmcnt(2)+bar (first 6
// of t+1).  vmcnt NEVER 0 in steady state (T4).
__global__ __launch_bounds__(512, 2) void k_gemm(
    const bf16* __restrict__ xb,    // [M][D] bf16
    const bf16* __restrict__ wi,    // [2D][D] bf16 interleaved
    const float* __restrict__ bx,
    const float* __restrict__ ba,
    const float* __restrict__ cv,
    unsigned int* __restrict__ pk)  // [M][D] packed (xn<<16 | la)
{
    __shared__ __align__(16) char smem[131072];  // 2 x 64KB buffers

    const int tid  = threadIdx.x;
    const int lane = tid & 63;
    const int w    = tid >> 6;       // 8 waves
    const int wm   = w >> 2;         // 0..1 (128 rows each)
    const int wn   = w & 3;          // 0..3 (64 cols each)

    const int orig = blockIdx.x;
    const int wgid = (orig & 7) * 128 + (orig >> 3);
    const int m0 = (wgid & 63) * 256;   // 64 M-blocks
    const int e0 = (wgid >> 6) * 256;   // 16 N-blocks (interleaved col space)

    const int srow  = lane >> 3;                 // 0..7
    const int swz16 = ((lane & 7) ^ srow) * 16;  // inverse-swizzled src chunk

    const char* gA = (const char*)xb;
    const char* gB = (const char*)wi;

// stage one 64-row unit u of A or B: every wave writes rows u*64+w*8..+7
#define SU_A(buf, kt, u) do {                                                  \
    const int rb_ = (u) * 64 + w * 8;                                          \
    async_copy16(smem + (buf) * 65536 + rb_ * 128,                             \
                 gA + ((long)(m0 + rb_ + srow) * 4096 +                        \
                       (long)(kt) * 128 + swz16));                             \
    } while (0)

#define SU_B(buf, kt, u) do {                                                  \
    const int rb_ = (u) * 64 + w * 8;                                          \
    async_copy16(smem + (buf) * 65536 + 32768 + rb_ * 128,                     \
                 gB + ((long)(e0 + rb_ + srow) * 4096 +                        \
                       (long)(kt) * 128 + swz16));                             \
    } while (0)

#define PHASE_GO() do {                                                        \
    asm volatile("s_waitcnt lgkmcnt(0)" ::: "memory");                         \
    __builtin_amdgcn_sched_barrier(0);                                         \
    __builtin_amdgcn_s_setprio(1); } while (0)
#define PHASE_DONE() __builtin_amdgcn_s_setprio(0)

    f32x4 acc[8][4];
#pragma unroll
    for (int i = 0; i < 8; ++i)
#pragma unroll
        for (int j = 0; j < 4; ++j) acc[i][j] = (f32x4)(0.0f);

    // prologue: tile 0 units in need-order; first 6 awaited, A1,A3 in flight
    SU_A(0, 0, 0); SU_A(0, 0, 2);
    SU_B(0, 0, 0); SU_B(0, 0, 1); SU_B(0, 0, 2); SU_B(0, 0, 3);
    SU_A(0, 0, 1); SU_A(0, 0, 3);
    asm volatile("s_waitcnt vmcnt(2)" ::: "memory");
    __builtin_amdgcn_s_barrier();

    const int rL = lane & 15;

    for (int kt = 0; kt < KTILES; ++kt) {
        const int c  = kt & 1;
        const int nb = 1 - c;
        char* sA = smem + c * 65536;
        char* sB = sA + 32768;
        const bool pf = (kt < KTILES - 1);

        bf16x8 af[4], bf[4];

#define LOAD_AF(ihalf, ks) do {                                                \
    _Pragma("unroll")                                                          \
    for (int i_ = 0; i_ < 4; ++i_) {                                           \
        const int r_ = wm * 128 + ((ihalf) * 4 + i_) * 16 + rL;                \
        const int ch_ = (((ks) * 4 + (lane >> 4)) ^ (r_ & 7)) * 16;            \
        af[i_] = *reinterpret_cast<const bf16x8*>(sA + r_ * 128 + ch_);        \
    } } while (0)

#define LOAD_BF(ks) do {                                                       \
    _Pragma("unroll")                                                          \
    for (int j_ = 0; j_ < 4; ++j_) {                                           \
        const int r_ = wn * 64 + j_ * 16 + rL;                                 \
        const int ch_ = (((ks) * 4 + (lane >> 4)) ^ (r_ & 7)) * 16;            \
        bf[j_] = *reinterpret_cast<const bf16x8*>(sB + r_ * 128 + ch_);        \
    } } while (0)

#define MFMA16(ihalf) do {                                                     \
    _Pragma("unroll")                                                          \
    for (int i_ = 0; i_ < 4; ++i_)                                             \
        _Pragma("unroll")                                                      \
        for (int j_ = 0; j_ < 4; ++j_)                                         \
            acc[(ihalf) * 4 + i_][j_] = __builtin_amdgcn_mfma_f32_16x16x32_bf16( \
                af[i_], bf[j_], acc[(ihalf) * 4 + i_][j_], 0, 0, 0);           \
    } while (0)

        // ---- phase 0: (ks0, ih0) reads A0/A2 + B ; stage A0,A2(t+1) ----
        LOAD_BF(0); LOAD_AF(0, 0);
        if (pf) { SU_A(nb, kt + 1, 0); SU_A(nb, kt + 1, 2); }
        PHASE_GO(); MFMA16(0); PHASE_DONE();
        // mid-tile: own A1,A3(t) landed; A0,A2(t+1) stay in flight
        if (pf) asm volatile("s_waitcnt vmcnt(2)" ::: "memory");
        else    asm volatile("s_waitcnt vmcnt(0)" ::: "memory");
        __builtin_amdgcn_s_barrier();

        // ---- phase 1: (ks0, ih1) reads A1/A3 ; stage B0,B1(t+1) ----
        LOAD_AF(1, 0);
        if (pf) { SU_B(nb, kt + 1, 0); SU_B(nb, kt + 1, 1); }
        PHASE_GO(); MFMA16(1); PHASE_DONE();

        // ---- phase 2: (ks1, ih0) ; stage B2,B3(t+1) ----
        LOAD_BF(1); LOAD_AF(0, 1);
        if (pf) { SU_B(nb, kt + 1, 2); SU_B(nb, kt + 1, 3); }
        PHASE_GO(); MFMA16(0); PHASE_DONE();

        // ---- phase 3: (ks1, ih1) ; stage A1,A3(t+1) ----
        LOAD_AF(1, 1);
        if (pf) { SU_A(nb, kt + 1, 1); SU_A(nb, kt + 1, 3); }
        PHASE_GO(); MFMA16(1); PHASE_DONE();

        // ---- boundary: first 6 units of t+1 landed; A1,A3(t+1) in flight ----
        if (pf) {
            asm volatile("s_waitcnt vmcnt(2)" ::: "memory");
            __builtin_amdgcn_s_barrier();
        }

#undef LOAD_AF
#undef LOAD_BF
#undef MFMA16
    }

#undef SU_A
#undef SU_B
#undef PHASE_GO
#undef PHASE_DONE

    // ---- epilogue: gates in-register, pack (bf16 xn | bf16 la) ----
    const int rgrp = lane >> 4;
    const int chb  = (e0 + wn * 64) >> 1;  // real channel base for this wave
#pragma unroll
    for (int jj = 0; jj < 2; ++jj) {
        const int ch = chb + jj * 16 + rL;
        const float bxv = bx[ch];
        const float bav = ba[ch];
        const float cvv = cv[ch];
#pragma unroll
        for (int i = 0; i < 8; ++i) {
#pragma unroll
            for (int r = 0; r < 4; ++r) {
                const int m = m0 + wm * 128 + i * 16 + rgrp * 4 + r;
                const float zx = acc[i][2 * jj][r] + bxv;
                const float za = acc[i][2 * jj + 1][r] + bav;
                const float gx = 1.0f / (1.0f + __expf(-zx));
                const float ga = 1.0f / (1.0f + __expf(-za));
                float la = cvv * ga;
                float mult = sqrtf(fmaxf(1.0f - __expf(2.0f * la), 0.0f));
                if (m < B_SZ) { la = -100.0f; mult = 1.0f; }  // s==0 reset
                const long o = (long)m * D_DIM + ch;
                const float xv = (float)xb[o];
                const float xn = xv * gx * mult;
                const unsigned int u =
                    ((unsigned int)bf16_bits(xn) << 16) | bf16_bits(la);
                pk[o] = u;
            }
        }
    }
}

// ---------------- scan: h = exp(la)*h + xn over S, y <- h --------------------
__global__ __launch_bounds__(64) void k_scan(
    const unsigned int* __restrict__ pk,
    float* __restrict__ y,
    const float* __restrict__ h0,
    float* __restrict__ hn) {
    const int c = blockIdx.x * 64 + threadIdx.x;  // chain id
    float h = h0[c];

    unsigned int u0[16], u1[16];
#pragma unroll
    for (int j = 0; j < 16; ++j) u0[j] = pk[(long)j * CHAINS + c];

    for (int g = 0; g < 128; g += 2) {
        const long base1 = ((long)(g + 1) * 16) * CHAINS + c;
        if (g + 1 < 128) {
#pragma unroll
            for (int j = 0; j < 16; ++j) u1[j] = pk[base1 + (long)j * CHAINS];
        }
        const long base0 = ((long)g * 16) * CHAINS + c;
#pragma unroll
        for (int j = 0; j < 16; ++j) {
            const unsigned int u = u0[j];
            const float la = __builtin_bit_cast(float, u << 16);
            const float xn = __builtin_bit_cast(float, u & 0xffff0000u);
            h = fmaf(__expf(la), h, xn);
            y[base0 + (long)j * CHAINS] = h;
        }
        const long base2 = ((long)(g + 2) * 16) * CHAINS + c;
        if (g + 2 < 128) {
#pragma unroll
            for (int j = 0; j < 16; ++j) u0[j] = pk[base2 + (long)j * CHAINS];
        }
        if (g + 1 < 128) {
#pragma unroll
            for (int j = 0; j < 16; ++j) {
                const unsigned int u = u1[j];
                const float la = __builtin_bit_cast(float, u << 16);
                const float xn = __builtin_bit_cast(float, u & 0xffff0000u);
                h = fmaf(__expf(la), h, xn);
                y[base1 + (long)j * CHAINS] = h;
            }
        }
    }
    hn[c] = h;
}

// ---------------- launch -----------------------------------------------------
extern "C" void kernel_launch(void* const* d_in, const int* in_sizes, int n_in,
                              void* d_out, int out_size, void* d_ws, size_t ws_size,
                              hipStream_t stream) {
    const float* x  = (const float*)d_in[0];
    const float* h0 = (const float*)d_in[1];
    const float* Wx = (const float*)d_in[2];
    const float* bx = (const float*)d_in[3];
    const float* Wa = (const float*)d_in[4];
    const float* ba = (const float*)d_in[5];
    const float* ap = (const float*)d_in[6];
    float* out = (float*)d_out;

    char* ws = (char*)d_ws;
    // ws: xb 0..64MiB | wi 64..80MiB | cv @80MiB | pk @80MiB+8KiB (64MiB)
    bf16*  xb = (bf16*)(ws);
    bf16*  wi = (bf16*)(ws + 67108864L);
    float* cv = (float*)(ws + 83886080L);
    unsigned int* pk = (unsigned int*)(ws + 83894272L);

    float* y  = out;                         // S*B*D
    float* hn = out + (long)M_DIM * D_DIM;   // B*D

    k_convert<<<dim3(2048), dim3(256), 0, stream>>>(
        (const float4*)x, (const float4*)Wx, (const float4*)Wa, xb, wi);
    k_cvec<<<dim3(8), dim3(256), 0, stream>>>(ap, cv);
    k_gemm<<<dim3((M_DIM / 256) * (2 * D_DIM / 256)), dim3(512), 0, stream>>>(
        xb, wi, bx, ba, cv, pk);
    k_scan<<<dim3(CHAINS / 64), dim3(64), 0, stream>>>(pk, y, h0, hn);
}